// Round 1
// baseline (1779.834 us; speedup 1.0000x reference)
//
#include <hip/hip_runtime.h>
#include <hip/hip_bf16.h>

#define NU 50000
#define NI 30000
#define NN 80000
#define EE 300000
#define E2 600000
#define EPSF 1e-12f
#define SLOPE_ 0.01f

__device__ __forceinline__ float wred64(float v){
  #pragma unroll
  for(int m=1;m<64;m<<=1) v += __shfl_xor(v, m, 64);
  return v;
}
__device__ __forceinline__ float leaky(float v){ return v>0.f? v : SLOPE_*v; }

// ---------------- CSR build ----------------
__global__ void k_hist(const int* __restrict__ eu, const int* __restrict__ ei, int* __restrict__ cnt){
  int e = blockIdx.x*blockDim.x + threadIdx.x;
  if(e<EE){ atomicAdd(&cnt[eu[e]],1); atomicAdd(&cnt[ei[e]],1); }
}

__global__ void k_scan(const int* __restrict__ cnt, int* __restrict__ ptr, int* __restrict__ cur){
  __shared__ int part[1024];
  int t = threadIdx.x;
  const int CH = (NN + 1023)/1024;   // 79
  int base = t*CH;
  int s = 0;
  for(int i=0;i<CH;i++){ int idx=base+i; if(idx<NN) s += cnt[idx]; }
  part[t] = s; __syncthreads();
  for(int off=1; off<1024; off<<=1){
    int v = (t>=off) ? part[t-off] : 0;
    __syncthreads();
    part[t] += v;
    __syncthreads();
  }
  int run = part[t] - s;   // exclusive prefix
  for(int i=0;i<CH;i++){
    int idx=base+i;
    if(idx<NN){ int c=cnt[idx]; ptr[idx]=run; cur[idx]=run; run+=c; }
  }
  if(t==0) ptr[NN] = E2;
}

__global__ void k_scatter(const int* __restrict__ eu, const int* __restrict__ ei,
                          int* __restrict__ cur, int* __restrict__ colA, int* __restrict__ dstA){
  int e = blockIdx.x*blockDim.x + threadIdx.x;
  if(e<EE){
    int u = eu[e], it = ei[e];
    int s1 = atomicAdd(&cur[u],1);  colA[s1]=it; dstA[s1]=u;
    int s2 = atomicAdd(&cur[it],1); colA[s2]=u;  dstA[s2]=it;
  }
}

// ---------------- l2norm rows (64 wide) ----------------
__global__ void k_l2n(const float* __restrict__ in, float* __restrict__ out, int rows){
  int idx = blockIdx.x*blockDim.x + threadIdx.x;
  int w = idx>>6, l = idx&63;
  if(w>=rows) return;
  float v = in[(size_t)w*64 + l];
  float ss = wred64(v*v);
  out[(size_t)w*64 + l] = v / sqrtf(ss + EPSF);
}

// ---------------- feature projection: leaky(feat@W+b) then l2norm ----------------
// block=256 (4 waves); wave: 4 row-groups (16 lanes each) x 4 rows = 16 rows; block = 64 rows.
template<int K>
__global__ __launch_bounds__(256) void k_proj(const float* __restrict__ feat,
    const float* __restrict__ W, const float* __restrict__ b,
    float* __restrict__ xout, int rows){
  int t = threadIdx.x;
  int wave = t>>6, lane = t&63;
  int rg = lane>>4, c16 = lane&15;
  int rowbase = blockIdx.x*64 + wave*16 + rg*4;
  const float* fr[4];
  float4 acc[4];
  int rid[4];
  #pragma unroll
  for(int r=0;r<4;r++){
    int row = rowbase + r;
    rid[r] = row;
    if(row > rows-1) row = rows-1;
    fr[r] = feat + (size_t)row*K;
    acc[r] = make_float4(0.f,0.f,0.f,0.f);
  }
  for(int k4=0;k4<K/4;k4++){
    float4 vf[4];
    #pragma unroll
    for(int r=0;r<4;r++) vf[r] = *(const float4*)(fr[r] + k4*4);
    #pragma unroll
    for(int j=0;j<4;j++){
      float4 w4 = *(const float4*)(W + (size_t)(k4*4+j)*64 + 4*c16);
      #pragma unroll
      for(int r=0;r<4;r++){
        float v = (j==0)?vf[r].x : (j==1)?vf[r].y : (j==2)?vf[r].z : vf[r].w;
        acc[r].x += v*w4.x; acc[r].y += v*w4.y; acc[r].z += v*w4.z; acc[r].w += v*w4.w;
      }
    }
  }
  float4 bb = *(const float4*)(b + 4*c16);
  #pragma unroll
  for(int r=0;r<4;r++){
    float4 o;
    o.x = leaky(acc[r].x + bb.x); o.y = leaky(acc[r].y + bb.y);
    o.z = leaky(acc[r].z + bb.z); o.w = leaky(acc[r].w + bb.w);
    float ss = o.x*o.x + o.y*o.y + o.z*o.z + o.w*o.w;
    #pragma unroll
    for(int m=1;m<16;m<<=1) ss += __shfl_xor(ss, m, 16);
    float inv = 1.f / sqrtf(ss + EPSF);
    o.x*=inv; o.y*=inv; o.z*=inv; o.w*=inv;
    if(rid[r] < rows) *(float4*)(xout + (size_t)rid[r]*64 + 4*c16) = o;
  }
}

// ---------------- routing GAT (items->users) + in-place pref update ----------------
__global__ void k_route(float* __restrict__ xv, float* __restrict__ xa,
    const int* __restrict__ ptr, const int* __restrict__ col){
  float* x = (blockIdx.y==0) ? xv : xa;
  int u = blockIdx.x*(blockDim.x>>6) + (threadIdx.x>>6);
  int l = threadIdx.x & 63;
  if(u >= NU) return;
  float xu = x[(size_t)u*64 + l];
  int e0 = ptr[u], e1 = ptr[u+1];
  float s = 0.f, acc = 0.f;
  for(int e=e0; e<e1; e++){
    int src = col[e];
    float xs = x[(size_t)src*64 + l];
    float d = wred64(xu*xs);
    float ea = __expf(d);          // rows are unit-norm -> d in [-1,1], no max needed
    s += ea; acc += ea*xs;
  }
  float nv = xu + acc/(s + EPSF);
  float ss = wred64(nv*nv);
  x[(size_t)u*64 + l] = nv / sqrtf(ss + EPSF);
}

// ---------------- final GAT over doubled edges; writes v_rep/a_rep + raw alphas ----------------
__global__ void k_fgat(const float* __restrict__ xv, const float* __restrict__ xa,
    float* __restrict__ av, float* __restrict__ aa,
    float* __restrict__ sv, float* __restrict__ sa,
    const int* __restrict__ ptr, const int* __restrict__ col,
    float* __restrict__ out){
  const float* x = (blockIdx.y==0) ? xv : xa;
  float* al = (blockIdx.y==0) ? av : aa;
  float* sb = (blockIdx.y==0) ? sv : sa;
  int i = blockIdx.x*(blockDim.x>>6) + (threadIdx.x>>6);
  int l = threadIdx.x & 63;
  if(i >= NN) return;
  float xi = x[(size_t)i*64 + l];
  int e0 = ptr[i], e1 = ptr[i+1];
  float s = 0.f, acc = 0.f;
  for(int e=e0; e<e1; e++){
    int src = col[e];
    float xs = x[(size_t)src*64 + l];
    float d = wred64(xi*xs);
    float ea = __expf(d);
    if(l==0) al[e] = ea;           // raw; normalized later via sb
    s += ea; acc += ea*xs;
  }
  float inv = 1.f/(s + EPSF);
  if(l==0) sb[i] = inv;
  float xh = leaky(acc*inv);
  out[(size_t)i*192 + 64 + 64*blockIdx.y + l] = xi + xh;
}

// ---------------- edge weights: relu(max(alpha_v*conf0, alpha_a*conf1)) ----------------
__global__ void k_weight(const float* __restrict__ av, const float* __restrict__ aa,
    const float* __restrict__ sv, const float* __restrict__ sa,
    const int* __restrict__ dstA, const float* __restrict__ conf, float* __restrict__ w){
  int e = blockIdx.x*blockDim.x + threadIdx.x;
  if(e >= E2) return;
  int d = dstA[e];
  float wv = av[e]*sv[d]*conf[2*d+0];
  float wa = aa[e]*sa[d]*conf[2*d+1];
  float m = fmaxf(wv, wa);
  w[e] = (m > 0.f) ? m : 0.f;
}

// ---------------- SAGE layer: leaky( (sum_e w*x[src]) @ Wm + bm ) ----------------
__global__ void k_egcn(const float* __restrict__ xin, const float* __restrict__ w,
    const int* __restrict__ ptr, const int* __restrict__ col,
    const float* __restrict__ Wm, const float* __restrict__ bm,
    float* __restrict__ xout){
  int i = blockIdx.x*(blockDim.x>>6) + (threadIdx.x>>6);
  int l = threadIdx.x & 63;
  if(i >= NN) return;
  int e0 = ptr[i], e1 = ptr[i+1];
  float acc = 0.f;
  for(int e=e0; e<e1; e++){
    acc += w[e] * xin[(size_t)col[e]*64 + l];
  }
  float o = bm[l];
  #pragma unroll
  for(int k=0;k<64;k++){
    float a = __shfl(acc, k, 64);
    o += a * Wm[k*64 + l];
  }
  xout[(size_t)i*64 + l] = leaky(o);
}

// second SAGE layer + final id_rep = x0 + x1 + x2 into out cols 0..63
__global__ void k_egcn2(const float* __restrict__ x0, const float* __restrict__ x1,
    const float* __restrict__ w,
    const int* __restrict__ ptr, const int* __restrict__ col,
    const float* __restrict__ Wm, const float* __restrict__ bm,
    float* __restrict__ out){
  int i = blockIdx.x*(blockDim.x>>6) + (threadIdx.x>>6);
  int l = threadIdx.x & 63;
  if(i >= NN) return;
  int e0 = ptr[i], e1 = ptr[i+1];
  float acc = 0.f;
  for(int e=e0; e<e1; e++){
    acc += w[e] * x1[(size_t)col[e]*64 + l];
  }
  float o = bm[l];
  #pragma unroll
  for(int k=0;k<64;k++){
    float a = __shfl(acc, k, 64);
    o += a * Wm[k*64 + l];
  }
  out[(size_t)i*192 + l] = x0[(size_t)i*64 + l] + x1[(size_t)i*64 + l] + leaky(o);
}

extern "C" void kernel_launch(void* const* d_in, const int* in_sizes, int n_in,
                              void* d_out, int out_size, void* d_ws, size_t ws_size,
                              hipStream_t stream){
  const int*   edge_u = (const int*)  d_in[0];
  const int*   edge_i = (const int*)  d_in[1];
  const float* v_feat = (const float*)d_in[2];
  const float* a_feat = (const float*)d_in[3];
  const float* pref_v = (const float*)d_in[4];
  const float* pref_a = (const float*)d_in[5];
  const float* Wv     = (const float*)d_in[6];
  const float* bv     = (const float*)d_in[7];
  const float* Wa     = (const float*)d_in[8];
  const float* ba     = (const float*)d_in[9];
  const float* id_emb = (const float*)d_in[10];
  const float* W1     = (const float*)d_in[11];
  const float* b1     = (const float*)d_in[12];
  const float* W2     = (const float*)d_in[13];
  const float* b2     = (const float*)d_in[14];
  const float* conf   = (const float*)d_in[15];
  float* out = (float*)d_out;

  char* p = (char*)d_ws;
  auto alloc = [&](size_t bytes)->void*{
    void* q = p; p += (bytes + 255) & ~(size_t)255; return q;
  };
  int*   cnt  = (int*)  alloc((size_t)NN*4);
  int*   ptr  = (int*)  alloc((size_t)(NN+1)*4);
  int*   cur  = (int*)  alloc((size_t)NN*4);
  int*   colA = (int*)  alloc((size_t)E2*4);
  int*   dstA = (int*)  alloc((size_t)E2*4);
  float* xv   = (float*)alloc((size_t)NN*64*4);
  float* xa   = (float*)alloc((size_t)NN*64*4);
  float* av   = (float*)alloc((size_t)E2*4);
  float* aa   = (float*)alloc((size_t)E2*4);
  float* sv   = (float*)alloc((size_t)NN*4);
  float* sa   = (float*)alloc((size_t)NN*4);
  float* wb   = (float*)alloc((size_t)E2*4);
  float* x0   = (float*)alloc((size_t)NN*64*4);
  float* x1   = (float*)alloc((size_t)NN*64*4);

  // CSR build (dst2 = [edge_u ; edge_i])
  hipMemsetAsync(cnt, 0, (size_t)NN*4, stream);
  k_hist<<<(EE+255)/256, 256, 0, stream>>>(edge_u, edge_i, cnt);
  k_scan<<<1, 1024, 0, stream>>>(cnt, ptr, cur);
  k_scatter<<<(EE+255)/256, 256, 0, stream>>>(edge_u, edge_i, cur, colA, dstA);

  // normalize prefs / id_emb
  k_l2n<<<(NU+3)/4, 256, 0, stream>>>(pref_v, xv, NU);
  k_l2n<<<(NU+3)/4, 256, 0, stream>>>(pref_a, xa, NU);
  k_l2n<<<(NN+3)/4, 256, 0, stream>>>(id_emb, x0, NN);

  // feature projections into item rows of x
  k_proj<2048><<<(NI+63)/64, 256, 0, stream>>>(v_feat, Wv, bv, xv + (size_t)NU*64, NI);
  k_proj<128> <<<(NI+63)/64, 256, 0, stream>>>(a_feat, Wa, ba, xa + (size_t)NU*64, NI);

  // 3 routing iterations (both modalities via grid.y)
  for(int it=0; it<3; ++it)
    k_route<<<dim3((NU+3)/4, 2), 256, 0, stream>>>(xv, xa, ptr, colA);

  // final GAT over doubled edges -> v_rep/a_rep + alphas
  k_fgat<<<dim3((NN+3)/4, 2), 256, 0, stream>>>(xv, xa, av, aa, sv, sa, ptr, colA, out);

  // edge weights
  k_weight<<<(E2+255)/256, 256, 0, stream>>>(av, aa, sv, sa, dstA, conf, wb);

  // egcn
  k_egcn <<<(NN+3)/4, 256, 0, stream>>>(x0, wb, ptr, colA, W1, b1, x1);
  k_egcn2<<<(NN+3)/4, 256, 0, stream>>>(x0, x1, wb, ptr, colA, W2, b2, out);
}

// Round 2
// 1265.679 us; speedup vs baseline: 1.4062x; 1.4062x over previous
//
#include <hip/hip_runtime.h>
#include <hip/hip_bf16.h>

#define NU 50000
#define NI 30000
#define NN 80000
#define EE 300000
#define E2 600000
#define EPSF 1e-12f
#define SLOPE_ 0.01f

__device__ __forceinline__ float leaky(float v){ return v>0.f? v : SLOPE_*v; }

// sum over the 16-lane group (xor masks 1,2,4,8 -> DPP row ops)
__device__ __forceinline__ float qred16(float v){
  v += __shfl_xor(v, 1, 16);
  v += __shfl_xor(v, 2, 16);
  v += __shfl_xor(v, 4, 16);
  v += __shfl_xor(v, 8, 16);
  return v;
}

// ---------------- CSR build ----------------
__global__ void k_hist(const int* __restrict__ eu, const int* __restrict__ ei, int* __restrict__ cnt){
  int e = blockIdx.x*blockDim.x + threadIdx.x;
  if(e<EE){ atomicAdd(&cnt[eu[e]],1); atomicAdd(&cnt[ei[e]],1); }
}

__global__ void k_scan(const int* __restrict__ cnt, int* __restrict__ ptr, int* __restrict__ cur){
  __shared__ int part[1024];
  int t = threadIdx.x;
  const int CH = (NN + 1023)/1024;   // 79
  int base = t*CH;
  int s = 0;
  for(int i=0;i<CH;i++){ int idx=base+i; if(idx<NN) s += cnt[idx]; }
  part[t] = s; __syncthreads();
  for(int off=1; off<1024; off<<=1){
    int v = (t>=off) ? part[t-off] : 0;
    __syncthreads();
    part[t] += v;
    __syncthreads();
  }
  int run = part[t] - s;   // exclusive prefix
  for(int i=0;i<CH;i++){
    int idx=base+i;
    if(idx<NN){ int c=cnt[idx]; ptr[idx]=run; cur[idx]=run; run+=c; }
  }
  if(t==0) ptr[NN] = E2;
}

__global__ void k_scatter(const int* __restrict__ eu, const int* __restrict__ ei,
                          int* __restrict__ cur, int* __restrict__ colA, int* __restrict__ dstA){
  int e = blockIdx.x*blockDim.x + threadIdx.x;
  if(e<EE){
    int u = eu[e], it = ei[e];
    int s1 = atomicAdd(&cur[u],1);  colA[s1]=it; dstA[s1]=u;
    int s2 = atomicAdd(&cur[it],1); colA[s2]=u;  dstA[s2]=it;
  }
}

// ---------------- l2norm rows (16-lane groups, float4) ----------------
__global__ void k_l2n4(const float* __restrict__ in, float* __restrict__ out, int rows){
  int idx = blockIdx.x*blockDim.x + threadIdx.x;
  int g = idx>>4, c = idx&15;
  if(g>=rows) return;
  float4 v = *(const float4*)(in + (size_t)g*64 + 4*c);
  float ss = qred16(v.x*v.x + v.y*v.y + v.z*v.z + v.w*v.w);
  float inv = 1.f/sqrtf(ss + EPSF);
  v.x*=inv; v.y*=inv; v.z*=inv; v.w*=inv;
  *(float4*)(out + (size_t)g*64 + 4*c) = v;
}

// ---------------- feature projection: l2norm(leaky(feat@W+b)) ----------------
// block = 256 threads = 4 waves; 16 rows per block.
// Compute phase: wave w handles K-chunk [w*K/4,(w+1)*K/4) for ALL 16 rows
//   (row-group rg=lane>>4 covers rows rg*4..rg*4+3; lane c=lane&15 owns cols 4c..4c+3).
// Partials through LDS, epilogue fused. Grid = rows/16 -> 4x the wave-parallelism
// of the round-1 kernel (occupancy 22% -> ~90% capacity).
template<int K>
__global__ __launch_bounds__(256) void k_projp(const float* __restrict__ feat,
    const float* __restrict__ W, const float* __restrict__ bias,
    float* __restrict__ xout, int rows){
  __shared__ float lds[4*16*68];
  const int CH = K/4;
  int t = threadIdx.x, wave = t>>6, lane = t&63, rg = lane>>4, c = lane&15;
  int rowb = blockIdx.x*16;
  const float* fr[4];
  float4 acc[4];
  #pragma unroll
  for(int r=0;r<4;r++){
    int row = rowb + rg*4 + r;
    if(row > rows-1) row = rows-1;
    fr[r] = feat + (size_t)row*K + wave*CH;
    acc[r] = make_float4(0.f,0.f,0.f,0.f);
  }
  for(int k4=0;k4<CH/4;k4++){
    float4 vf[4];
    #pragma unroll
    for(int r=0;r<4;r++) vf[r] = *(const float4*)(fr[r] + k4*4);
    #pragma unroll
    for(int j=0;j<4;j++){
      float4 w4 = *(const float4*)(W + (size_t)(wave*CH + k4*4 + j)*64 + 4*c);
      #pragma unroll
      for(int r=0;r<4;r++){
        float v = (j==0)?vf[r].x : (j==1)?vf[r].y : (j==2)?vf[r].z : vf[r].w;
        acc[r].x += v*w4.x; acc[r].y += v*w4.y; acc[r].z += v*w4.z; acc[r].w += v*w4.w;
      }
    }
  }
  #pragma unroll
  for(int r=0;r<4;r++){
    float* p = lds + ((size_t)wave*16 + rg*4 + r)*68 + 4*c;
    p[0]=acc[r].x; p[1]=acc[r].y; p[2]=acc[r].z; p[3]=acc[r].w;
  }
  __syncthreads();
  // reduce phase: row-in-block = wave*4 + rg
  int rib = wave*4 + rg;
  int row = rowb + rib;
  float4 o = make_float4(0.f,0.f,0.f,0.f);
  #pragma unroll
  for(int v=0; v<4; v++){
    const float* p = lds + ((size_t)v*16 + rib)*68 + 4*c;
    o.x += p[0]; o.y += p[1]; o.z += p[2]; o.w += p[3];
  }
  float4 bb = *(const float4*)(bias + 4*c);
  o.x = leaky(o.x + bb.x); o.y = leaky(o.y + bb.y);
  o.z = leaky(o.z + bb.z); o.w = leaky(o.w + bb.w);
  float ss = qred16(o.x*o.x + o.y*o.y + o.z*o.z + o.w*o.w);
  float inv = 1.f/sqrtf(ss + EPSF);
  if(row < rows){
    float4 st = make_float4(o.x*inv, o.y*inv, o.z*inv, o.w*inv);
    *(float4*)(xout + (size_t)row*64 + 4*c) = st;
  }
}

// ---------------- routing GAT (items->users), in-place pref update ----------------
// one 16-lane group per user; lane holds float4 of the row
__global__ void k_route(float* __restrict__ xv, float* __restrict__ xa,
    const int* __restrict__ ptr, const int* __restrict__ col){
  float* x = (blockIdx.y==0) ? xv : xa;
  int g = blockIdx.x*(blockDim.x>>4) + (threadIdx.x>>4);
  int c = threadIdx.x & 15;
  if(g >= NU) return;
  float4 xu = *(const float4*)(x + (size_t)g*64 + 4*c);
  int e0 = ptr[g], e1 = ptr[g+1];
  float s = 0.f;
  float4 acc = make_float4(0.f,0.f,0.f,0.f);
  for(int e=e0; e<e1; e++){
    int src = col[e];
    float4 xs = *(const float4*)(x + (size_t)src*64 + 4*c);
    float d = qred16(xu.x*xs.x + xu.y*xs.y + xu.z*xs.z + xu.w*xs.w);
    float ea = __expf(d);          // rows unit-norm -> d in [-1,1], no max pass needed
    s += ea;
    acc.x += ea*xs.x; acc.y += ea*xs.y; acc.z += ea*xs.z; acc.w += ea*xs.w;
  }
  float inv = 1.f/(s + EPSF);
  float4 nv = make_float4(xu.x + acc.x*inv, xu.y + acc.y*inv,
                          xu.z + acc.z*inv, xu.w + acc.w*inv);
  float ss = qred16(nv.x*nv.x + nv.y*nv.y + nv.z*nv.z + nv.w*nv.w);
  float r = 1.f/sqrtf(ss + EPSF);
  nv.x*=r; nv.y*=r; nv.z*=r; nv.w*=r;
  *(float4*)(x + (size_t)g*64 + 4*c) = nv;
}

// ---------------- final GAT over doubled edges ----------------
__global__ void k_fgat(const float* __restrict__ xv, const float* __restrict__ xa,
    float* __restrict__ av, float* __restrict__ aa,
    float* __restrict__ sv, float* __restrict__ sa,
    const int* __restrict__ ptr, const int* __restrict__ col,
    float* __restrict__ out){
  const float* x = (blockIdx.y==0) ? xv : xa;
  float* al = (blockIdx.y==0) ? av : aa;
  float* sb = (blockIdx.y==0) ? sv : sa;
  int g = blockIdx.x*(blockDim.x>>4) + (threadIdx.x>>4);
  int c = threadIdx.x & 15;
  if(g >= NN) return;
  float4 xi = *(const float4*)(x + (size_t)g*64 + 4*c);
  int e0 = ptr[g], e1 = ptr[g+1];
  float s = 0.f;
  float4 acc = make_float4(0.f,0.f,0.f,0.f);
  for(int e=e0; e<e1; e++){
    int src = col[e];
    float4 xs = *(const float4*)(x + (size_t)src*64 + 4*c);
    float d = qred16(xi.x*xs.x + xi.y*xs.y + xi.z*xs.z + xi.w*xs.w);
    float ea = __expf(d);
    if(c==0) al[e] = ea;           // raw; normalized by sb in k_weight
    s += ea;
    acc.x += ea*xs.x; acc.y += ea*xs.y; acc.z += ea*xs.z; acc.w += ea*xs.w;
  }
  float inv = 1.f/(s + EPSF);
  if(c==0) sb[g] = inv;
  float4 o;
  o.x = xi.x + leaky(acc.x*inv); o.y = xi.y + leaky(acc.y*inv);
  o.z = xi.z + leaky(acc.z*inv); o.w = xi.w + leaky(acc.w*inv);
  *(float4*)(out + (size_t)g*192 + 64 + 64*blockIdx.y + 4*c) = o;
}

// ---------------- edge weights ----------------
__global__ void k_weight(const float* __restrict__ av, const float* __restrict__ aa,
    const float* __restrict__ sv, const float* __restrict__ sa,
    const int* __restrict__ dstA, const float* __restrict__ conf, float* __restrict__ w){
  int e = blockIdx.x*blockDim.x + threadIdx.x;
  if(e >= E2) return;
  int d = dstA[e];
  float wv = av[e]*sv[d]*conf[2*d+0];
  float wa = aa[e]*sa[d]*conf[2*d+1];
  float m = fmaxf(wv, wa);
  w[e] = (m > 0.f) ? m : 0.f;
}

// ---------------- weighted aggregation (shuffle-free) ----------------
__global__ void k_agg(const float* __restrict__ xin, const float* __restrict__ w,
    const int* __restrict__ ptr, const int* __restrict__ col, float* __restrict__ agg){
  int g = blockIdx.x*(blockDim.x>>4) + (threadIdx.x>>4);
  int c = threadIdx.x & 15;
  if(g >= NN) return;
  int e0 = ptr[g], e1 = ptr[g+1];
  float4 acc = make_float4(0.f,0.f,0.f,0.f);
  for(int e=e0; e<e1; e++){
    float we = w[e];
    float4 xs = *(const float4*)(xin + (size_t)col[e]*64 + 4*c);
    acc.x += we*xs.x; acc.y += we*xs.y; acc.z += we*xs.z; acc.w += we*xs.w;
  }
  *(float4*)(agg + (size_t)g*64 + 4*c) = acc;
}

// ---------------- 64x64 dense layer: leaky(A@W+b) (+ optional residual sum) ----------------
// wave = 4 rows (rg each 1 row), block = 16 rows
template<int EPI>   // 0: out=leaky(..), stride 64; 1: out = a0+a1+leaky(..), stride 192
__global__ __launch_bounds__(256) void k_mm64(const float* __restrict__ A,
    const float* __restrict__ W, const float* __restrict__ bias,
    const float* __restrict__ a0, const float* __restrict__ a1,
    float* __restrict__ out){
  int t = threadIdx.x, wave = t>>6, lane = t&63, rg = lane>>4, c = lane&15;
  int row = blockIdx.x*16 + wave*4 + rg;
  if(row >= NN) return;
  const float* ar = A + (size_t)row*64;
  float4 acc = make_float4(0.f,0.f,0.f,0.f);
  #pragma unroll
  for(int k4=0;k4<16;k4++){
    float4 a4 = *(const float4*)(ar + k4*4);
    #pragma unroll
    for(int j=0;j<4;j++){
      float4 w4 = *(const float4*)(W + (size_t)(k4*4+j)*64 + 4*c);
      float v = (j==0)?a4.x : (j==1)?a4.y : (j==2)?a4.z : a4.w;
      acc.x += v*w4.x; acc.y += v*w4.y; acc.z += v*w4.z; acc.w += v*w4.w;
    }
  }
  float4 bb = *(const float4*)(bias + 4*c);
  acc.x = leaky(acc.x + bb.x); acc.y = leaky(acc.y + bb.y);
  acc.z = leaky(acc.z + bb.z); acc.w = leaky(acc.w + bb.w);
  if(EPI==0){
    *(float4*)(out + (size_t)row*64 + 4*c) = acc;
  }else{
    float4 v0 = *(const float4*)(a0 + (size_t)row*64 + 4*c);
    float4 v1 = *(const float4*)(a1 + (size_t)row*64 + 4*c);
    acc.x += v0.x + v1.x; acc.y += v0.y + v1.y;
    acc.z += v0.z + v1.z; acc.w += v0.w + v1.w;
    *(float4*)(out + (size_t)row*192 + 4*c) = acc;
  }
}

extern "C" void kernel_launch(void* const* d_in, const int* in_sizes, int n_in,
                              void* d_out, int out_size, void* d_ws, size_t ws_size,
                              hipStream_t stream){
  const int*   edge_u = (const int*)  d_in[0];
  const int*   edge_i = (const int*)  d_in[1];
  const float* v_feat = (const float*)d_in[2];
  const float* a_feat = (const float*)d_in[3];
  const float* pref_v = (const float*)d_in[4];
  const float* pref_a = (const float*)d_in[5];
  const float* Wv     = (const float*)d_in[6];
  const float* bv     = (const float*)d_in[7];
  const float* Wa     = (const float*)d_in[8];
  const float* ba     = (const float*)d_in[9];
  const float* id_emb = (const float*)d_in[10];
  const float* W1     = (const float*)d_in[11];
  const float* b1     = (const float*)d_in[12];
  const float* W2     = (const float*)d_in[13];
  const float* b2     = (const float*)d_in[14];
  const float* conf   = (const float*)d_in[15];
  float* out = (float*)d_out;

  char* p = (char*)d_ws;
  auto alloc = [&](size_t bytes)->void*{
    void* q = p; p += (bytes + 255) & ~(size_t)255; return q;
  };
  int*   cnt  = (int*)  alloc((size_t)NN*4);
  int*   ptr  = (int*)  alloc((size_t)(NN+1)*4);
  int*   cur  = (int*)  alloc((size_t)NN*4);
  int*   colA = (int*)  alloc((size_t)E2*4);
  int*   dstA = (int*)  alloc((size_t)E2*4);
  float* xv   = (float*)alloc((size_t)NN*64*4);
  float* xa   = (float*)alloc((size_t)NN*64*4);
  float* av   = (float*)alloc((size_t)E2*4);
  float* aa   = (float*)alloc((size_t)E2*4);
  float* sv   = (float*)alloc((size_t)NN*4);
  float* sa   = (float*)alloc((size_t)NN*4);
  float* wb   = (float*)alloc((size_t)E2*4);
  float* x0   = (float*)alloc((size_t)NN*64*4);
  float* x1   = (float*)alloc((size_t)NN*64*4);
  // agg aliases xv: xv is dead after k_fgat/k_weight, agg used only after
  float* agg  = xv;

  // CSR build (dst2 = [edge_u ; edge_i])
  hipMemsetAsync(cnt, 0, (size_t)NN*4, stream);
  k_hist<<<(EE+255)/256, 256, 0, stream>>>(edge_u, edge_i, cnt);
  k_scan<<<1, 1024, 0, stream>>>(cnt, ptr, cur);
  k_scatter<<<(EE+255)/256, 256, 0, stream>>>(edge_u, edge_i, cur, colA, dstA);

  // normalize prefs / id_emb (16 lanes per row)
  k_l2n4<<<(NU*16+255)/256, 256, 0, stream>>>(pref_v, xv, NU);
  k_l2n4<<<(NU*16+255)/256, 256, 0, stream>>>(pref_a, xa, NU);
  k_l2n4<<<(NN*16+255)/256, 256, 0, stream>>>(id_emb, x0, NN);

  // feature projections into item rows of x
  k_projp<2048><<<(NI+15)/16, 256, 0, stream>>>(v_feat, Wv, bv, xv + (size_t)NU*64, NI);
  k_projp<128> <<<(NI+15)/16, 256, 0, stream>>>(a_feat, Wa, ba, xa + (size_t)NU*64, NI);

  // 3 routing iterations (both modalities via grid.y)
  for(int it=0; it<3; ++it)
    k_route<<<dim3((NU+15)/16, 2), 256, 0, stream>>>(xv, xa, ptr, colA);

  // final GAT over doubled edges -> v_rep/a_rep + raw alphas
  k_fgat<<<dim3((NN+15)/16, 2), 256, 0, stream>>>(xv, xa, av, aa, sv, sa, ptr, colA, out);

  // edge weights
  k_weight<<<(E2+255)/256, 256, 0, stream>>>(av, aa, sv, sa, dstA, conf, wb);

  // egcn: agg + 64x64 GEMM, twice
  k_agg<<<(NN+15)/16, 256, 0, stream>>>(x0, wb, ptr, colA, agg);
  k_mm64<0><<<(NN+15)/16, 256, 0, stream>>>(agg, W1, b1, nullptr, nullptr, x1);
  k_agg<<<(NN+15)/16, 256, 0, stream>>>(x1, wb, ptr, colA, agg);
  k_mm64<1><<<(NN+15)/16, 256, 0, stream>>>(agg, W2, b2, x0, x1, out);
}

// Round 3
// 964.135 us; speedup vs baseline: 1.8460x; 1.3128x over previous
//
#include <hip/hip_runtime.h>
#include <hip/hip_bf16.h>

#define NU 50000
#define NI 30000
#define NN 80000
#define EE 300000
#define E2 600000
#define EPSF 1e-12f
#define SLOPE_ 0.01f

__device__ __forceinline__ float leaky(float v){ return v>0.f? v : SLOPE_*v; }

__device__ __forceinline__ float qred16(float v){
  v += __shfl_xor(v, 1, 16);
  v += __shfl_xor(v, 2, 16);
  v += __shfl_xor(v, 4, 16);
  v += __shfl_xor(v, 8, 16);
  return v;
}
__device__ __forceinline__ float4 qnorm(float4 v){
  float ss = qred16(v.x*v.x + v.y*v.y + v.z*v.z + v.w*v.w);
  float inv = 1.f/sqrtf(ss + EPSF);
  v.x*=inv; v.y*=inv; v.z*=inv; v.w*=inv;
  return v;
}

typedef __attribute__((address_space(3))) unsigned int lds_u32;
typedef const __attribute__((address_space(1))) unsigned int glb_u32;
__device__ __forceinline__ void gld16(const float* g, float* l){
  __builtin_amdgcn_global_load_lds((glb_u32*)g, (lds_u32*)l, 16, 0, 0);
}

// ---------------- CSR build ----------------
__global__ void k_hist(const int* __restrict__ eu, const int* __restrict__ ei, int* __restrict__ cnt){
  int e = blockIdx.x*blockDim.x + threadIdx.x;
  if(e<EE){ atomicAdd(&cnt[eu[e]],1); atomicAdd(&cnt[ei[e]],1); }
}

__global__ void k_scan(const int* __restrict__ cnt, int* __restrict__ ptr, int* __restrict__ cur){
  __shared__ int part[1024];
  int t = threadIdx.x;
  const int CH = (NN + 1023)/1024;
  int base = t*CH;
  int s = 0;
  for(int i=0;i<CH;i++){ int idx=base+i; if(idx<NN) s += cnt[idx]; }
  part[t] = s; __syncthreads();
  for(int off=1; off<1024; off<<=1){
    int v = (t>=off) ? part[t-off] : 0;
    __syncthreads();
    part[t] += v;
    __syncthreads();
  }
  int run = part[t] - s;
  for(int i=0;i<CH;i++){
    int idx=base+i;
    if(idx<NN){ int c=cnt[idx]; ptr[idx]=run; cur[idx]=run; run+=c; }
  }
  if(t==0) ptr[NN] = E2;
}

__global__ void k_scatter(const int* __restrict__ eu, const int* __restrict__ ei,
                          int* __restrict__ cur, int* __restrict__ colA, int* __restrict__ dstA){
  int e = blockIdx.x*blockDim.x + threadIdx.x;
  if(e<EE){
    int u = eu[e], it = ei[e];
    int s1 = atomicAdd(&cur[u],1);  colA[s1]=it; dstA[s1]=u;
    int s2 = atomicAdd(&cur[it],1); colA[s2]=u;  dstA[s2]=it;
  }
}

// ---------------- l2norm rows ----------------
__global__ void k_l2n4(const float* __restrict__ in, float* __restrict__ out, int rows){
  int idx = blockIdx.x*blockDim.x + threadIdx.x;
  int g = idx>>4, c = idx&15;
  if(g>=rows) return;
  float4 v = *(const float4*)(in + (size_t)g*64 + 4*c);
  *(float4*)(out + (size_t)g*64 + 4*c) = qnorm(v);
}

// ---------------- tiled fp32 GEMM: part[ks] = feat[:, ks-slice] @ W[ks-slice, :] ----------------
// BM=64, BN=64, BK=64; 256 threads; thread (rg=t>>4, c=t&15) owns rows 4rg..+3, cols 4c..+3.
// A-tile staged with XOR-4 swizzle on 16B segments (pre-swizzled global source).
template<int K, int KS>
__global__ __launch_bounds__(256,4) void k_pg(const float* __restrict__ feat,
    const float* __restrict__ W, float* __restrict__ part, int rows){
  __shared__ float As[64*64];
  __shared__ float Ws[64*64];
  const int KSL = K/KS;
  const int STEPS = KSL/64;
  int t = threadIdx.x;
  int w = t>>6, lane = t&63;
  int c = t&15, rg = t>>4;
  int rowb = blockIdx.x*64;
  int k0 = blockIdx.y*KSL;
  float4 acc[4];
  #pragma unroll
  for(int r=0;r<4;r++) acc[r] = make_float4(0.f,0.f,0.f,0.f);

  for(int s=0; s<STEPS; ++s){
    if(s) __syncthreads();
    int kk = k0 + s*64;
    #pragma unroll
    for(int i=0;i<4;i++){
      int q = w*4 + i;                       // row-quad 0..15
      int trow = q*4 + (lane>>4);
      int grow = rowb + trow; if(grow > rows-1) grow = rows-1;
      int seg = (lane&15) ^ (q&3);           // pre-swizzled source segment
      gld16(feat + (size_t)grow*K + kk + seg*4, As + q*256);
    }
    #pragma unroll
    for(int i=0;i<4;i++){
      int q = w*4 + i;                       // W rows kk+4q..+3, linear
      gld16(W + (size_t)(kk + q*4)*64 + lane*4, Ws + q*256);
    }
    __syncthreads();                         // drains vmcnt before barrier
    #pragma unroll 4
    for(int k4=0;k4<16;k4++){
      float4 wv[4], a4[4];
      #pragma unroll
      for(int j=0;j<4;j++) wv[j] = *(const float4*)&Ws[(k4*4+j)*64 + c*4];
      int sw = (k4 ^ (rg&3))*4;              // un-swizzle on read
      #pragma unroll
      for(int r=0;r<4;r++) a4[r] = *(const float4*)&As[(rg*4+r)*64 + sw];
      #pragma unroll
      for(int r=0;r<4;r++){
        acc[r].x += a4[r].x*wv[0].x + a4[r].y*wv[1].x + a4[r].z*wv[2].x + a4[r].w*wv[3].x;
        acc[r].y += a4[r].x*wv[0].y + a4[r].y*wv[1].y + a4[r].z*wv[2].y + a4[r].w*wv[3].y;
        acc[r].z += a4[r].x*wv[0].z + a4[r].y*wv[1].z + a4[r].z*wv[2].z + a4[r].w*wv[3].z;
        acc[r].w += a4[r].x*wv[0].w + a4[r].y*wv[1].w + a4[r].z*wv[2].w + a4[r].w*wv[3].w;
      }
    }
  }
  float* pb = part + (size_t)blockIdx.y*rows*64;
  #pragma unroll
  for(int r=0;r<4;r++){
    int row = rowb + rg*4 + r;
    if(row < rows) *(float4*)(pb + (size_t)row*64 + c*4) = acc[r];
  }
}

// reduce K-split partials + bias + leaky + l2norm
template<int KS>
__global__ void k_projfin(const float* __restrict__ part, const float* __restrict__ bias,
    float* __restrict__ xout, int rows){
  int idx = blockIdx.x*blockDim.x + threadIdx.x;
  int g = idx>>4, c = idx&15;
  if(g>=rows) return;
  float4 o = make_float4(0.f,0.f,0.f,0.f);
  #pragma unroll
  for(int s=0;s<KS;s++){
    float4 p = *(const float4*)(part + ((size_t)s*rows + g)*64 + 4*c);
    o.x += p.x; o.y += p.y; o.z += p.z; o.w += p.w;
  }
  float4 bb = *(const float4*)(bias + 4*c);
  o.x = leaky(o.x + bb.x); o.y = leaky(o.y + bb.y);
  o.z = leaky(o.z + bb.z); o.w = leaky(o.w + bb.w);
  *(float4*)(xout + (size_t)g*64 + 4*c) = qnorm(o);
}

// ---------------- fused 3-iteration routing, both modalities ----------------
// items never change during routing; user rows stay in registers across iterations.
__global__ void k_route3(const float* __restrict__ pv, const float* __restrict__ pa,
    float* __restrict__ xv, float* __restrict__ xa,
    const int* __restrict__ ptr, const int* __restrict__ col){
  int g = blockIdx.x*(blockDim.x>>4) + (threadIdx.x>>4);
  int c = threadIdx.x & 15;
  if(g >= NU) return;
  float4 uv = qnorm(*(const float4*)(pv + (size_t)g*64 + 4*c));
  float4 ua = qnorm(*(const float4*)(pa + (size_t)g*64 + 4*c));
  int e0 = ptr[g], e1 = ptr[g+1];
  #pragma unroll 1
  for(int it=0; it<3; ++it){
    float sv = 0.f, sa = 0.f;
    float4 cv = make_float4(0.f,0.f,0.f,0.f);
    float4 ca = make_float4(0.f,0.f,0.f,0.f);
    for(int e=e0; e<e1; e++){
      int src = col[e];
      float4 jv = *(const float4*)(xv + (size_t)src*64 + 4*c);
      float4 ja = *(const float4*)(xa + (size_t)src*64 + 4*c);
      float dv = qred16(uv.x*jv.x + uv.y*jv.y + uv.z*jv.z + uv.w*jv.w);
      float da = qred16(ua.x*ja.x + ua.y*ja.y + ua.z*ja.z + ua.w*ja.w);
      float ev = __expf(dv), ea = __expf(da);
      sv += ev; sa += ea;
      cv.x += ev*jv.x; cv.y += ev*jv.y; cv.z += ev*jv.z; cv.w += ev*jv.w;
      ca.x += ea*ja.x; ca.y += ea*ja.y; ca.z += ea*ja.z; ca.w += ea*ja.w;
    }
    float iv = 1.f/(sv + EPSF), ia = 1.f/(sa + EPSF);
    uv = qnorm(make_float4(uv.x + cv.x*iv, uv.y + cv.y*iv, uv.z + cv.z*iv, uv.w + cv.w*iv));
    ua = qnorm(make_float4(ua.x + ca.x*ia, ua.y + ca.y*ia, ua.z + ca.z*ia, ua.w + ca.w*ia));
  }
  *(float4*)(xv + (size_t)g*64 + 4*c) = uv;
  *(float4*)(xa + (size_t)g*64 + 4*c) = ua;
}

// ---------------- final GAT over doubled edges, both modalities ----------------
__global__ void k_fgat(const float* __restrict__ xv, const float* __restrict__ xa,
    float* __restrict__ av, float* __restrict__ aa,
    float* __restrict__ sv, float* __restrict__ sa,
    const int* __restrict__ ptr, const int* __restrict__ col,
    float* __restrict__ out){
  int g = blockIdx.x*(blockDim.x>>4) + (threadIdx.x>>4);
  int c = threadIdx.x & 15;
  if(g >= NN) return;
  float4 iv = *(const float4*)(xv + (size_t)g*64 + 4*c);
  float4 ia = *(const float4*)(xa + (size_t)g*64 + 4*c);
  int e0 = ptr[g], e1 = ptr[g+1];
  float smv = 0.f, sma = 0.f;
  float4 cv = make_float4(0.f,0.f,0.f,0.f);
  float4 ca = make_float4(0.f,0.f,0.f,0.f);
  for(int e=e0; e<e1; e++){
    int src = col[e];
    float4 jv = *(const float4*)(xv + (size_t)src*64 + 4*c);
    float4 ja = *(const float4*)(xa + (size_t)src*64 + 4*c);
    float dv = qred16(iv.x*jv.x + iv.y*jv.y + iv.z*jv.z + iv.w*jv.w);
    float da = qred16(ia.x*ja.x + ia.y*ja.y + ia.z*ja.z + ia.w*ja.w);
    float ev = __expf(dv), ea = __expf(da);
    if(c==0){ av[e] = ev; aa[e] = ea; }
    smv += ev; sma += ea;
    cv.x += ev*jv.x; cv.y += ev*jv.y; cv.z += ev*jv.z; cv.w += ev*jv.w;
    ca.x += ea*ja.x; ca.y += ea*ja.y; ca.z += ea*ja.z; ca.w += ea*ja.w;
  }
  float invv = 1.f/(smv + EPSF), inva = 1.f/(sma + EPSF);
  if(c==0){ sv[g] = invv; sa[g] = inva; }
  float4 ov = make_float4(iv.x + leaky(cv.x*invv), iv.y + leaky(cv.y*invv),
                          iv.z + leaky(cv.z*invv), iv.w + leaky(cv.w*invv));
  float4 oa = make_float4(ia.x + leaky(ca.x*inva), ia.y + leaky(ca.y*inva),
                          ia.z + leaky(ca.z*inva), ia.w + leaky(ca.w*inva));
  *(float4*)(out + (size_t)g*192 + 64  + 4*c) = ov;
  *(float4*)(out + (size_t)g*192 + 128 + 4*c) = oa;
}

// ---------------- edge weights ----------------
__global__ void k_weight(const float* __restrict__ av, const float* __restrict__ aa,
    const float* __restrict__ sv, const float* __restrict__ sa,
    const int* __restrict__ dstA, const float* __restrict__ conf, float* __restrict__ w){
  int e = blockIdx.x*blockDim.x + threadIdx.x;
  if(e >= E2) return;
  int d = dstA[e];
  float wv = av[e]*sv[d]*conf[2*d+0];
  float wa = aa[e]*sa[d]*conf[2*d+1];
  float m = fmaxf(wv, wa);
  w[e] = (m > 0.f) ? m : 0.f;
}

// ---------------- fused SAGE: leaky((sum_e w*x[src]) @ Wm + b) (+residual epi) ----------------
template<int EPI>   // 0: out=leaky(..) stride 64; 1: out = a0+a1+leaky(..) stride 192
__global__ __launch_bounds__(256) void k_aggmm(const float* __restrict__ xin,
    const float* __restrict__ wb, const int* __restrict__ ptr, const int* __restrict__ col,
    const float* __restrict__ Wm, const float* __restrict__ bm,
    const float* __restrict__ a0, const float* __restrict__ a1,
    float* __restrict__ outp){
  __shared__ float Wl[64*64];
  __shared__ float rowbuf[16*68];
  int t = threadIdx.x;
  #pragma unroll
  for(int i=0;i<4;i++)
    *(float4*)&Wl[i*1024 + t*4] = *(const float4*)&Wm[i*1024 + t*4];
  int grp = t>>4, c = t&15;
  int g = blockIdx.x*16 + grp;
  bool ok = g < NN;
  int e0 = ok ? ptr[g] : 0, e1 = ok ? ptr[g+1] : 0;
  float4 acc = make_float4(0.f,0.f,0.f,0.f);
  for(int e=e0; e<e1; e++){
    float we = wb[e];
    float4 xs = *(const float4*)(xin + (size_t)col[e]*64 + 4*c);
    acc.x += we*xs.x; acc.y += we*xs.y; acc.z += we*xs.z; acc.w += we*xs.w;
  }
  __syncthreads();                       // Wl visible
  *(float4*)&rowbuf[grp*68 + c*4] = acc; // same-wave write->read, no barrier needed
  float4 o = make_float4(0.f,0.f,0.f,0.f);
  #pragma unroll 4
  for(int k4=0;k4<16;k4++){
    float4 a4 = *(const float4*)&rowbuf[grp*68 + k4*4];
    float4 w0 = *(const float4*)&Wl[(k4*4+0)*64 + c*4];
    float4 w1 = *(const float4*)&Wl[(k4*4+1)*64 + c*4];
    float4 w2 = *(const float4*)&Wl[(k4*4+2)*64 + c*4];
    float4 w3 = *(const float4*)&Wl[(k4*4+3)*64 + c*4];
    o.x += a4.x*w0.x + a4.y*w1.x + a4.z*w2.x + a4.w*w3.x;
    o.y += a4.x*w0.y + a4.y*w1.y + a4.z*w2.y + a4.w*w3.y;
    o.z += a4.x*w0.z + a4.y*w1.z + a4.z*w2.z + a4.w*w3.z;
    o.w += a4.x*w0.w + a4.y*w1.w + a4.z*w2.w + a4.w*w3.w;
  }
  if(!ok) return;
  float4 bb = *(const float4*)(bm + 4*c);
  o.x = leaky(o.x + bb.x); o.y = leaky(o.y + bb.y);
  o.z = leaky(o.z + bb.z); o.w = leaky(o.w + bb.w);
  if(EPI==0){
    *(float4*)(outp + (size_t)g*64 + 4*c) = o;
  }else{
    float4 v0 = *(const float4*)(a0 + (size_t)g*64 + 4*c);
    float4 v1 = *(const float4*)(a1 + (size_t)g*64 + 4*c);
    o.x += v0.x + v1.x; o.y += v0.y + v1.y;
    o.z += v0.z + v1.z; o.w += v0.w + v1.w;
    *(float4*)(outp + (size_t)g*192 + 4*c) = o;
  }
}

extern "C" void kernel_launch(void* const* d_in, const int* in_sizes, int n_in,
                              void* d_out, int out_size, void* d_ws, size_t ws_size,
                              hipStream_t stream){
  const int*   edge_u = (const int*)  d_in[0];
  const int*   edge_i = (const int*)  d_in[1];
  const float* v_feat = (const float*)d_in[2];
  const float* a_feat = (const float*)d_in[3];
  const float* pref_v = (const float*)d_in[4];
  const float* pref_a = (const float*)d_in[5];
  const float* Wv     = (const float*)d_in[6];
  const float* bv     = (const float*)d_in[7];
  const float* Wa     = (const float*)d_in[8];
  const float* ba     = (const float*)d_in[9];
  const float* id_emb = (const float*)d_in[10];
  const float* W1     = (const float*)d_in[11];
  const float* b1     = (const float*)d_in[12];
  const float* W2     = (const float*)d_in[13];
  const float* b2     = (const float*)d_in[14];
  const float* conf   = (const float*)d_in[15];
  float* out = (float*)d_out;

  char* p = (char*)d_ws;
  auto alloc = [&](size_t bytes)->void*{
    void* q = p; p += (bytes + 255) & ~(size_t)255; return q;
  };
  int*   cnt  = (int*)  alloc((size_t)NN*4);
  int*   ptr  = (int*)  alloc((size_t)(NN+1)*4);
  int*   cur  = (int*)  alloc((size_t)NN*4);
  int*   colA = (int*)  alloc((size_t)E2*4);
  int*   dstA = (int*)  alloc((size_t)E2*4);
  float* xv   = (float*)alloc((size_t)NN*64*4);
  float* xa   = (float*)alloc((size_t)NN*64*4);
  float* x0   = (float*)alloc((size_t)NN*64*4);   // partial GEMM buffer aliases x0+x1
  float* x1   = (float*)alloc((size_t)NN*64*4);
  float* av   = (float*)alloc((size_t)E2*4);
  float* aa   = (float*)alloc((size_t)E2*4);
  float* sv   = (float*)alloc((size_t)NN*4);
  float* sa   = (float*)alloc((size_t)NN*4);
  float* wb   = (float*)alloc((size_t)E2*4);
  float* part = x0;  // 4*NI*64*4 = 30.7MB <= x0+x1 (41MB); dead before x0/x1 written

  // CSR build (dst2 = [edge_u ; edge_i])
  hipMemsetAsync(cnt, 0, (size_t)NN*4, stream);
  k_hist<<<(EE+255)/256, 256, 0, stream>>>(edge_u, edge_i, cnt);
  k_scan<<<1, 1024, 0, stream>>>(cnt, ptr, cur);
  k_scatter<<<(EE+255)/256, 256, 0, stream>>>(edge_u, edge_i, cur, colA, dstA);

  // feature projections (tiled GEMM with k-split, then reduce+epilogue)
  k_pg<2048,4><<<dim3((NI+63)/64, 4), 256, 0, stream>>>(v_feat, Wv, part, NI);
  k_projfin<4><<<(NI*16+255)/256, 256, 0, stream>>>(part, bv, xv + (size_t)NU*64, NI);
  k_pg<128,2><<<dim3((NI+63)/64, 2), 256, 0, stream>>>(a_feat, Wa, part, NI);
  k_projfin<2><<<(NI*16+255)/256, 256, 0, stream>>>(part, ba, xa + (size_t)NU*64, NI);

  // id_emb l2norm (after part is dead - aliased)
  k_l2n4<<<(NN*16+255)/256, 256, 0, stream>>>(id_emb, x0, NN);

  // fused 3-iteration routing (both modalities, pref l2norm folded in)
  k_route3<<<(NU+15)/16, 256, 0, stream>>>(pref_v, pref_a, xv, xa, ptr, colA);

  // final GAT (both modalities) -> v_rep/a_rep + raw alphas
  k_fgat<<<(NN+15)/16, 256, 0, stream>>>(xv, xa, av, aa, sv, sa, ptr, colA, out);

  // edge weights
  k_weight<<<(E2+255)/256, 256, 0, stream>>>(av, aa, sv, sa, dstA, conf, wb);

  // egcn: fused agg+dense, twice
  k_aggmm<0><<<(NN+15)/16, 256, 0, stream>>>(x0, wb, ptr, colA, W1, b1, nullptr, nullptr, x1);
  k_aggmm<1><<<(NN+15)/16, 256, 0, stream>>>(x1, wb, ptr, colA, W2, b2, x0, x1, out);
}

// Round 4
// 751.294 us; speedup vs baseline: 2.3690x; 1.2833x over previous
//
#include <hip/hip_runtime.h>
#include <hip/hip_bf16.h>

#define NU 50000
#define NI 30000
#define NN 80000
#define EE 300000
#define E2 600000
#define EPSF 1e-12f
#define SLOPE_ 0.01f
#define NB_SCAN ((NN + 255)/256)   // 313

__device__ __forceinline__ float leaky(float v){ return v>0.f? v : SLOPE_*v; }

__device__ __forceinline__ float qred16(float v){
  v += __shfl_xor(v, 1, 16);
  v += __shfl_xor(v, 2, 16);
  v += __shfl_xor(v, 4, 16);
  v += __shfl_xor(v, 8, 16);
  return v;
}
__device__ __forceinline__ float4 qnorm(float4 v){
  float ss = qred16(v.x*v.x + v.y*v.y + v.z*v.z + v.w*v.w);
  float inv = 1.f/sqrtf(ss + EPSF);
  v.x*=inv; v.y*=inv; v.z*=inv; v.w*=inv;
  return v;
}

typedef __attribute__((address_space(3))) unsigned int lds_u32;
typedef const __attribute__((address_space(1))) unsigned int glb_u32;
__device__ __forceinline__ void gld16(const float* g, float* l){
  __builtin_amdgcn_global_load_lds((glb_u32*)g, (lds_u32*)l, 16, 0, 0);
}

// ---------------- CSR build ----------------
__global__ void k_hist(const int* __restrict__ eu, const int* __restrict__ ei, int* __restrict__ cnt){
  int e = blockIdx.x*blockDim.x + threadIdx.x;
  if(e<EE){ atomicAdd(&cnt[eu[e]],1); atomicAdd(&cnt[ei[e]],1); }
}

// hierarchical exclusive scan over cnt[NN]
__global__ void k_scanA(const int* __restrict__ cnt, int* __restrict__ loc, int* __restrict__ bsum){
  __shared__ int sm[256];
  int t = threadIdx.x;
  int i = blockIdx.x*256 + t;
  int v = (i<NN) ? cnt[i] : 0;
  sm[t] = v; __syncthreads();
  #pragma unroll
  for(int off=1; off<256; off<<=1){
    int u = (t>=off) ? sm[t-off] : 0;
    __syncthreads();
    sm[t] += u;
    __syncthreads();
  }
  if(i<NN) loc[i] = sm[t] - v;          // exclusive within block
  if(t==255) bsum[blockIdx.x] = sm[255];
}

__global__ void k_scanB(int* __restrict__ bsum, int* __restrict__ boff){
  __shared__ int sm[512];
  int t = threadIdx.x;
  int v = (t<NB_SCAN) ? bsum[t] : 0;
  sm[t] = v; __syncthreads();
  #pragma unroll
  for(int off=1; off<512; off<<=1){
    int u = (t>=off) ? sm[t-off] : 0;
    __syncthreads();
    sm[t] += u;
    __syncthreads();
  }
  if(t<NB_SCAN) boff[t] = sm[t] - v;    // exclusive across blocks
}

__global__ void k_scanC(const int* __restrict__ loc, const int* __restrict__ boff,
                        int* __restrict__ ptr, int* __restrict__ cur){
  int i = blockIdx.x*256 + threadIdx.x;
  if(i<NN){
    int p = loc[i] + boff[blockIdx.x];
    ptr[i] = p; cur[i] = p;
  }
  if(i==0) ptr[NN] = E2;
}

__global__ void k_scatter(const int* __restrict__ eu, const int* __restrict__ ei,
                          int* __restrict__ cur, int* __restrict__ colA, int* __restrict__ dstA){
  int e = blockIdx.x*blockDim.x + threadIdx.x;
  if(e<EE){
    int u = eu[e], it = ei[e];
    int s1 = atomicAdd(&cur[u],1);  colA[s1]=it; dstA[s1]=u;
    int s2 = atomicAdd(&cur[it],1); colA[s2]=u;  dstA[s2]=it;
  }
}

// ---------------- l2norm rows (stride 64) ----------------
__global__ void k_l2n4(const float* __restrict__ in, float* __restrict__ out, int rows){
  int idx = blockIdx.x*blockDim.x + threadIdx.x;
  int g = idx>>4, c = idx&15;
  if(g>=rows) return;
  float4 v = *(const float4*)(in + (size_t)g*64 + 4*c);
  *(float4*)(out + (size_t)g*64 + 4*c) = qnorm(v);
}

// ---------------- tiled fp32 GEMM: part[ks] = feat[:, ks-slice] @ W[ks-slice, :] ----------------
template<int K, int KS>
__global__ __launch_bounds__(256,4) void k_pg(const float* __restrict__ feat,
    const float* __restrict__ W, float* __restrict__ part, int rows){
  __shared__ float As[64*64];
  __shared__ float Ws[64*64];
  const int KSL = K/KS;
  const int STEPS = KSL/64;
  int t = threadIdx.x;
  int w = t>>6, lane = t&63;
  int c = t&15, rg = t>>4;
  int rowb = blockIdx.x*64;
  int k0 = blockIdx.y*KSL;
  float4 acc[4];
  #pragma unroll
  for(int r=0;r<4;r++) acc[r] = make_float4(0.f,0.f,0.f,0.f);

  for(int s=0; s<STEPS; ++s){
    if(s) __syncthreads();
    int kk = k0 + s*64;
    #pragma unroll
    for(int i=0;i<4;i++){
      int q = w*4 + i;
      int trow = q*4 + (lane>>4);
      int grow = rowb + trow; if(grow > rows-1) grow = rows-1;
      int seg = (lane&15) ^ (q&3);
      gld16(feat + (size_t)grow*K + kk + seg*4, As + q*256);
    }
    #pragma unroll
    for(int i=0;i<4;i++){
      int q = w*4 + i;
      gld16(W + (size_t)(kk + q*4)*64 + lane*4, Ws + q*256);
    }
    __syncthreads();
    #pragma unroll 4
    for(int k4=0;k4<16;k4++){
      float4 wv[4], a4[4];
      #pragma unroll
      for(int j=0;j<4;j++) wv[j] = *(const float4*)&Ws[(k4*4+j)*64 + c*4];
      int sw = (k4 ^ (rg&3))*4;
      #pragma unroll
      for(int r=0;r<4;r++) a4[r] = *(const float4*)&As[(rg*4+r)*64 + sw];
      #pragma unroll
      for(int r=0;r<4;r++){
        acc[r].x += a4[r].x*wv[0].x + a4[r].y*wv[1].x + a4[r].z*wv[2].x + a4[r].w*wv[3].x;
        acc[r].y += a4[r].x*wv[0].y + a4[r].y*wv[1].y + a4[r].z*wv[2].y + a4[r].w*wv[3].y;
        acc[r].z += a4[r].x*wv[0].z + a4[r].y*wv[1].z + a4[r].z*wv[2].z + a4[r].w*wv[3].z;
        acc[r].w += a4[r].x*wv[0].w + a4[r].y*wv[1].w + a4[r].z*wv[2].w + a4[r].w*wv[3].w;
      }
    }
  }
  float* pb = part + (size_t)blockIdx.y*rows*64;
  #pragma unroll
  for(int r=0;r<4;r++){
    int row = rowb + rg*4 + r;
    if(row < rows) *(float4*)(pb + (size_t)row*64 + c*4) = acc[r];
  }
}

// reduce K-split partials + bias + leaky + l2norm -> interleaved xc (row stride 128)
template<int KS>
__global__ void k_projfin(const float* __restrict__ part, const float* __restrict__ bias,
    float* __restrict__ xout, int rows){
  int idx = blockIdx.x*blockDim.x + threadIdx.x;
  int g = idx>>4, c = idx&15;
  if(g>=rows) return;
  float4 o = make_float4(0.f,0.f,0.f,0.f);
  #pragma unroll
  for(int s=0;s<KS;s++){
    float4 p = *(const float4*)(part + ((size_t)s*rows + g)*64 + 4*c);
    o.x += p.x; o.y += p.y; o.z += p.z; o.w += p.w;
  }
  float4 bb = *(const float4*)(bias + 4*c);
  o.x = leaky(o.x + bb.x); o.y = leaky(o.y + bb.y);
  o.z = leaky(o.z + bb.z); o.w = leaky(o.w + bb.w);
  *(float4*)(xout + (size_t)g*128 + 4*c) = qnorm(o);
}

// ---------------- fused 3-iteration routing, both modalities (interleaved xc) ----------------
__global__ void k_route3(const float* __restrict__ pv, const float* __restrict__ pa,
    float* __restrict__ xc, const int* __restrict__ ptr, const int* __restrict__ col){
  int g = blockIdx.x*(blockDim.x>>4) + (threadIdx.x>>4);
  int c = threadIdx.x & 15;
  if(g >= NU) return;
  float4 uv = qnorm(*(const float4*)(pv + (size_t)g*64 + 4*c));
  float4 ua = qnorm(*(const float4*)(pa + (size_t)g*64 + 4*c));
  int e0 = ptr[g], e1 = ptr[g+1];
  #pragma unroll 1
  for(int it=0; it<3; ++it){
    float sv = 0.f, sa = 0.f;
    float4 cv = make_float4(0.f,0.f,0.f,0.f);
    float4 ca = make_float4(0.f,0.f,0.f,0.f);
    for(int e=e0; e<e1; e++){
      int src = col[e];
      float4 jv = *(const float4*)(xc + (size_t)src*128 + 4*c);
      float4 ja = *(const float4*)(xc + (size_t)src*128 + 64 + 4*c);
      float dv = qred16(uv.x*jv.x + uv.y*jv.y + uv.z*jv.z + uv.w*jv.w);
      float da = qred16(ua.x*ja.x + ua.y*ja.y + ua.z*ja.z + ua.w*ja.w);
      float ev = __expf(dv), ea = __expf(da);
      sv += ev; sa += ea;
      cv.x += ev*jv.x; cv.y += ev*jv.y; cv.z += ev*jv.z; cv.w += ev*jv.w;
      ca.x += ea*ja.x; ca.y += ea*ja.y; ca.z += ea*ja.z; ca.w += ea*ja.w;
    }
    float iv = 1.f/(sv + EPSF), ia = 1.f/(sa + EPSF);
    uv = qnorm(make_float4(uv.x + cv.x*iv, uv.y + cv.y*iv, uv.z + cv.z*iv, uv.w + cv.w*iv));
    ua = qnorm(make_float4(ua.x + ca.x*ia, ua.y + ca.y*ia, ua.z + ca.z*ia, ua.w + ca.w*ia));
  }
  *(float4*)(xc + (size_t)g*128 + 4*c) = uv;
  *(float4*)(xc + (size_t)g*128 + 64 + 4*c) = ua;
}

// ---------------- final GAT over doubled edges, both modalities ----------------
__global__ void k_fgat(const float* __restrict__ xc,
    float* __restrict__ av, float* __restrict__ aa,
    float* __restrict__ sv, float* __restrict__ sa,
    const int* __restrict__ ptr, const int* __restrict__ col,
    float* __restrict__ out){
  int g = blockIdx.x*(blockDim.x>>4) + (threadIdx.x>>4);
  int c = threadIdx.x & 15;
  if(g >= NN) return;
  float4 iv = *(const float4*)(xc + (size_t)g*128 + 4*c);
  float4 ia = *(const float4*)(xc + (size_t)g*128 + 64 + 4*c);
  int e0 = ptr[g], e1 = ptr[g+1];
  float smv = 0.f, sma = 0.f;
  float4 cv = make_float4(0.f,0.f,0.f,0.f);
  float4 ca = make_float4(0.f,0.f,0.f,0.f);
  for(int e=e0; e<e1; e++){
    int src = col[e];
    float4 jv = *(const float4*)(xc + (size_t)src*128 + 4*c);
    float4 ja = *(const float4*)(xc + (size_t)src*128 + 64 + 4*c);
    float dv = qred16(iv.x*jv.x + iv.y*jv.y + iv.z*jv.z + iv.w*jv.w);
    float da = qred16(ia.x*ja.x + ia.y*ja.y + ia.z*ja.z + ia.w*ja.w);
    float ev = __expf(dv), ea = __expf(da);
    if(c==0){ av[e] = ev; aa[e] = ea; }
    smv += ev; sma += ea;
    cv.x += ev*jv.x; cv.y += ev*jv.y; cv.z += ev*jv.z; cv.w += ev*jv.w;
    ca.x += ea*ja.x; ca.y += ea*ja.y; ca.z += ea*ja.z; ca.w += ea*ja.w;
  }
  float invv = 1.f/(smv + EPSF), inva = 1.f/(sma + EPSF);
  if(c==0){ sv[g] = invv; sa[g] = inva; }
  float4 ov = make_float4(iv.x + leaky(cv.x*invv), iv.y + leaky(cv.y*invv),
                          iv.z + leaky(cv.z*invv), iv.w + leaky(cv.w*invv));
  float4 oa = make_float4(ia.x + leaky(ca.x*inva), ia.y + leaky(ca.y*inva),
                          ia.z + leaky(ca.z*inva), ia.w + leaky(ca.w*inva));
  *(float4*)(out + (size_t)g*192 + 64  + 4*c) = ov;
  *(float4*)(out + (size_t)g*192 + 128 + 4*c) = oa;
}

// ---------------- edge weights ----------------
__global__ void k_weight(const float* __restrict__ av, const float* __restrict__ aa,
    const float* __restrict__ sv, const float* __restrict__ sa,
    const int* __restrict__ dstA, const float* __restrict__ conf, float* __restrict__ w){
  int e = blockIdx.x*blockDim.x + threadIdx.x;
  if(e >= E2) return;
  int d = dstA[e];
  float wv = av[e]*sv[d]*conf[2*d+0];
  float wa = aa[e]*sa[d]*conf[2*d+1];
  float m = fmaxf(wv, wa);
  w[e] = (m > 0.f) ? m : 0.f;
}

// ---------------- fused SAGE: leaky((sum_e w*x[src]) @ Wm + b) (+residual epi) ----------------
template<int EPI>
__global__ __launch_bounds__(256) void k_aggmm(const float* __restrict__ xin,
    const float* __restrict__ wb, const int* __restrict__ ptr, const int* __restrict__ col,
    const float* __restrict__ Wm, const float* __restrict__ bm,
    const float* __restrict__ a0, const float* __restrict__ a1,
    float* __restrict__ outp){
  __shared__ float Wl[64*64];
  __shared__ float rowbuf[16*68];
  int t = threadIdx.x;
  #pragma unroll
  for(int i=0;i<4;i++)
    *(float4*)&Wl[i*1024 + t*4] = *(const float4*)&Wm[i*1024 + t*4];
  int grp = t>>4, c = t&15;
  int g = blockIdx.x*16 + grp;
  bool ok = g < NN;
  int e0 = ok ? ptr[g] : 0, e1 = ok ? ptr[g+1] : 0;
  float4 acc = make_float4(0.f,0.f,0.f,0.f);
  for(int e=e0; e<e1; e++){
    float we = wb[e];
    float4 xs = *(const float4*)(xin + (size_t)col[e]*64 + 4*c);
    acc.x += we*xs.x; acc.y += we*xs.y; acc.z += we*xs.z; acc.w += we*xs.w;
  }
  __syncthreads();
  *(float4*)&rowbuf[grp*68 + c*4] = acc;
  float4 o = make_float4(0.f,0.f,0.f,0.f);
  #pragma unroll 4
  for(int k4=0;k4<16;k4++){
    float4 a4 = *(const float4*)&rowbuf[grp*68 + k4*4];
    float4 w0 = *(const float4*)&Wl[(k4*4+0)*64 + c*4];
    float4 w1 = *(const float4*)&Wl[(k4*4+1)*64 + c*4];
    float4 w2 = *(const float4*)&Wl[(k4*4+2)*64 + c*4];
    float4 w3 = *(const float4*)&Wl[(k4*4+3)*64 + c*4];
    o.x += a4.x*w0.x + a4.y*w1.x + a4.z*w2.x + a4.w*w3.x;
    o.y += a4.x*w0.y + a4.y*w1.y + a4.z*w2.y + a4.w*w3.y;
    o.z += a4.x*w0.z + a4.y*w1.z + a4.z*w2.z + a4.w*w3.z;
    o.w += a4.x*w0.w + a4.y*w1.w + a4.z*w2.w + a4.w*w3.w;
  }
  if(!ok) return;
  float4 bb = *(const float4*)(bm + 4*c);
  o.x = leaky(o.x + bb.x); o.y = leaky(o.y + bb.y);
  o.z = leaky(o.z + bb.z); o.w = leaky(o.w + bb.w);
  if(EPI==0){
    *(float4*)(outp + (size_t)g*64 + 4*c) = o;
  }else{
    float4 v0 = *(const float4*)(a0 + (size_t)g*64 + 4*c);
    float4 v1 = *(const float4*)(a1 + (size_t)g*64 + 4*c);
    o.x += v0.x + v1.x; o.y += v0.y + v1.y;
    o.z += v0.z + v1.z; o.w += v0.w + v1.w;
    *(float4*)(outp + (size_t)g*192 + 4*c) = o;
  }
}

extern "C" void kernel_launch(void* const* d_in, const int* in_sizes, int n_in,
                              void* d_out, int out_size, void* d_ws, size_t ws_size,
                              hipStream_t stream){
  const int*   edge_u = (const int*)  d_in[0];
  const int*   edge_i = (const int*)  d_in[1];
  const float* v_feat = (const float*)d_in[2];
  const float* a_feat = (const float*)d_in[3];
  const float* pref_v = (const float*)d_in[4];
  const float* pref_a = (const float*)d_in[5];
  const float* Wv     = (const float*)d_in[6];
  const float* bv     = (const float*)d_in[7];
  const float* Wa     = (const float*)d_in[8];
  const float* ba     = (const float*)d_in[9];
  const float* id_emb = (const float*)d_in[10];
  const float* W1     = (const float*)d_in[11];
  const float* b1     = (const float*)d_in[12];
  const float* W2     = (const float*)d_in[13];
  const float* b2     = (const float*)d_in[14];
  const float* conf   = (const float*)d_in[15];
  float* out = (float*)d_out;

  char* p = (char*)d_ws;
  auto alloc = [&](size_t bytes)->void*{
    void* q = p; p += (bytes + 255) & ~(size_t)255; return q;
  };
  int*   cnt  = (int*)  alloc((size_t)NN*4);
  int*   loc  = (int*)  alloc((size_t)NN*4);
  int*   bsum = (int*)  alloc((size_t)NB_SCAN*4);
  int*   boff = (int*)  alloc((size_t)NB_SCAN*4);
  int*   ptr  = (int*)  alloc((size_t)(NN+1)*4);
  int*   cur  = (int*)  alloc((size_t)NN*4);
  int*   colA = (int*)  alloc((size_t)E2*4);
  int*   dstA = (int*)  alloc((size_t)E2*4);
  float* xc   = (float*)alloc((size_t)NN*128*4);  // interleaved [v|a] per node
  float* x0   = (float*)alloc((size_t)NN*64*4);   // GEMM partials alias x0+x1
  float* x1   = (float*)alloc((size_t)NN*64*4);
  float* av   = (float*)alloc((size_t)E2*4);
  float* aa   = (float*)alloc((size_t)E2*4);
  float* sv   = (float*)alloc((size_t)NN*4);
  float* sa   = (float*)alloc((size_t)NN*4);
  float* wb   = (float*)alloc((size_t)E2*4);
  float* part = x0;  // 4*NI*64*4 = 30.7MB <= x0+x1 (41MB); dead before x0/x1 written

  // CSR build (dst2 = [edge_u ; edge_i])
  hipMemsetAsync(cnt, 0, (size_t)NN*4, stream);
  k_hist<<<(EE+255)/256, 256, 0, stream>>>(edge_u, edge_i, cnt);
  k_scanA<<<NB_SCAN, 256, 0, stream>>>(cnt, loc, bsum);
  k_scanB<<<1, 512, 0, stream>>>(bsum, boff);
  k_scanC<<<NB_SCAN, 256, 0, stream>>>(loc, boff, ptr, cur);
  k_scatter<<<(EE+255)/256, 256, 0, stream>>>(edge_u, edge_i, cur, colA, dstA);

  // feature projections (tiled GEMM with k-split, then reduce+epilogue into xc item rows)
  k_pg<2048,4><<<dim3((NI+63)/64, 4), 256, 0, stream>>>(v_feat, Wv, part, NI);
  k_projfin<4><<<(NI*16+255)/256, 256, 0, stream>>>(part, bv, xc + (size_t)NU*128, NI);
  k_pg<128,2><<<dim3((NI+63)/64, 2), 256, 0, stream>>>(a_feat, Wa, part, NI);
  k_projfin<2><<<(NI*16+255)/256, 256, 0, stream>>>(part, ba, xc + (size_t)NU*128 + 64, NI);

  // id_emb l2norm (part is dead now)
  k_l2n4<<<(NN*16+255)/256, 256, 0, stream>>>(id_emb, x0, NN);

  // fused 3-iteration routing (both modalities, pref l2norm folded in)
  k_route3<<<(NU+15)/16, 256, 0, stream>>>(pref_v, pref_a, xc, ptr, colA);

  // final GAT (both modalities) -> v_rep/a_rep + raw alphas
  k_fgat<<<(NN+15)/16, 256, 0, stream>>>(xc, av, aa, sv, sa, ptr, colA, out);

  // edge weights
  k_weight<<<(E2+255)/256, 256, 0, stream>>>(av, aa, sv, sa, dstA, conf, wb);

  // egcn: fused agg+dense, twice
  k_aggmm<0><<<(NN+15)/16, 256, 0, stream>>>(x0, wb, ptr, colA, W1, b1, nullptr, nullptr, x1);
  k_aggmm<1><<<(NN+15)/16, 256, 0, stream>>>(x1, wb, ptr, colA, W2, b2, x0, x1, out);
}

// Round 5
// 736.801 us; speedup vs baseline: 2.4156x; 1.0197x over previous
//
#include <hip/hip_runtime.h>
#include <hip/hip_bf16.h>

#define NU 50000
#define NI 30000
#define NN 80000
#define EE 300000
#define E2 600000
#define EPSF 1e-12f
#define SLOPE_ 0.01f
#define NB_SCAN ((NN + 255)/256)   // 313

__device__ __forceinline__ float leaky(float v){ return v>0.f? v : SLOPE_*v; }

__device__ __forceinline__ float qred16(float v){
  v += __shfl_xor(v, 1, 16);
  v += __shfl_xor(v, 2, 16);
  v += __shfl_xor(v, 4, 16);
  v += __shfl_xor(v, 8, 16);
  return v;
}
__device__ __forceinline__ float4 qnorm(float4 v){
  float ss = qred16(v.x*v.x + v.y*v.y + v.z*v.z + v.w*v.w);
  float inv = 1.f/sqrtf(ss + EPSF);
  v.x*=inv; v.y*=inv; v.z*=inv; v.w*=inv;
  return v;
}
__device__ __forceinline__ float dot4(float4 a, float4 b){
  return a.x*b.x + a.y*b.y + a.z*b.z + a.w*b.w;
}

typedef __attribute__((address_space(3))) unsigned int lds_u32;
typedef const __attribute__((address_space(1))) unsigned int glb_u32;
__device__ __forceinline__ void gld16(const float* g, float* l){
  __builtin_amdgcn_global_load_lds((glb_u32*)g, (lds_u32*)l, 16, 0, 0);
}

// ---------------- CSR build ----------------
__global__ void k_hist(const int* __restrict__ eu, const int* __restrict__ ei, int* __restrict__ cnt){
  int e = blockIdx.x*blockDim.x + threadIdx.x;
  if(e<EE){ atomicAdd(&cnt[eu[e]],1); atomicAdd(&cnt[ei[e]],1); }
}

__global__ void k_scanA(const int* __restrict__ cnt, int* __restrict__ loc, int* __restrict__ bsum){
  __shared__ int sm[256];
  int t = threadIdx.x;
  int i = blockIdx.x*256 + t;
  int v = (i<NN) ? cnt[i] : 0;
  sm[t] = v; __syncthreads();
  #pragma unroll
  for(int off=1; off<256; off<<=1){
    int u = (t>=off) ? sm[t-off] : 0;
    __syncthreads();
    sm[t] += u;
    __syncthreads();
  }
  if(i<NN) loc[i] = sm[t] - v;
  if(t==255) bsum[blockIdx.x] = sm[255];
}

__global__ void k_scanB(int* __restrict__ bsum, int* __restrict__ boff){
  __shared__ int sm[512];
  int t = threadIdx.x;
  int v = (t<NB_SCAN) ? bsum[t] : 0;
  sm[t] = v; __syncthreads();
  #pragma unroll
  for(int off=1; off<512; off<<=1){
    int u = (t>=off) ? sm[t-off] : 0;
    __syncthreads();
    sm[t] += u;
    __syncthreads();
  }
  if(t<NB_SCAN) boff[t] = sm[t] - v;
}

__global__ void k_scanC(const int* __restrict__ loc, const int* __restrict__ boff,
                        int* __restrict__ ptr, int* __restrict__ cur){
  int i = blockIdx.x*256 + threadIdx.x;
  if(i<NN){
    int p = loc[i] + boff[blockIdx.x];
    ptr[i] = p; cur[i] = p;
  }
  if(i==0) ptr[NN] = E2;
}

__global__ void k_scatter(const int* __restrict__ eu, const int* __restrict__ ei,
                          int* __restrict__ cur, int* __restrict__ colA){
  int e = blockIdx.x*blockDim.x + threadIdx.x;
  if(e<EE){
    int u = eu[e], it = ei[e];
    int s1 = atomicAdd(&cur[u],1);  colA[s1]=it;
    int s2 = atomicAdd(&cur[it],1); colA[s2]=u;
  }
}

// ---------------- l2norm rows (stride 64) ----------------
__global__ void k_l2n4(const float* __restrict__ in, float* __restrict__ out, int rows){
  int idx = blockIdx.x*blockDim.x + threadIdx.x;
  int g = idx>>4, c = idx&15;
  if(g>=rows) return;
  float4 v = *(const float4*)(in + (size_t)g*64 + 4*c);
  *(float4*)(out + (size_t)g*64 + 4*c) = qnorm(v);
}

// ---------------- tiled fp32 GEMM, BM=128 (for K=2048) ----------------
// thread (rg=t>>4, c=t&15) owns rows rg*8..+7, cols 4c..+3 of the 128x64 tile.
template<int K, int KS>
__global__ __launch_bounds__(256,4) void k_pg128(const float* __restrict__ feat,
    const float* __restrict__ W, float* __restrict__ part, int rows){
  __shared__ float As[128*64];
  __shared__ float Ws[64*64];
  const int KSL = K/KS;
  const int STEPS = KSL/64;
  int t = threadIdx.x;
  int w = t>>6, lane = t&63;
  int c = t&15, rg = t>>4;
  int rowb = blockIdx.x*128;
  int k0 = blockIdx.y*KSL;
  float4 acc[8];
  #pragma unroll
  for(int r=0;r<8;r++) acc[r] = make_float4(0.f,0.f,0.f,0.f);

  for(int s=0; s<STEPS; ++s){
    if(s) __syncthreads();
    int kk = k0 + s*64;
    #pragma unroll
    for(int i=0;i<8;i++){
      int q = w*8 + i;                       // row-quad 0..31
      int grow = rowb + q*4 + (lane>>4); if(grow > rows-1) grow = rows-1;
      int seg = (lane&15) ^ (q&3);           // segment-swizzled source
      gld16(feat + (size_t)grow*K + kk + seg*4, As + q*256);
    }
    #pragma unroll
    for(int i=0;i<4;i++){
      int q = w*4 + i;
      gld16(W + (size_t)(kk + q*4)*64 + lane*4, Ws + q*256);
    }
    __syncthreads();
    #pragma unroll 2
    for(int k4=0;k4<16;k4++){
      float4 wv[4];
      #pragma unroll
      for(int j=0;j<4;j++) wv[j] = *(const float4*)&Ws[(k4*4+j)*64 + c*4];
      #pragma unroll
      for(int r=0;r<8;r++){
        int row = rg*8 + r;
        int sw = (k4 ^ ((row>>2)&3))*4;      // un-swizzle on read
        float4 a4 = *(const float4*)&As[row*64 + sw];
        acc[r].x += a4.x*wv[0].x + a4.y*wv[1].x + a4.z*wv[2].x + a4.w*wv[3].x;
        acc[r].y += a4.x*wv[0].y + a4.y*wv[1].y + a4.z*wv[2].y + a4.w*wv[3].y;
        acc[r].z += a4.x*wv[0].z + a4.y*wv[1].z + a4.z*wv[2].z + a4.w*wv[3].z;
        acc[r].w += a4.x*wv[0].w + a4.y*wv[1].w + a4.z*wv[2].w + a4.w*wv[3].w;
      }
    }
  }
  float* pb = part + (size_t)blockIdx.y*rows*64;
  #pragma unroll
  for(int r=0;r<8;r++){
    int row = rowb + rg*8 + r;
    if(row < rows) *(float4*)(pb + (size_t)row*64 + c*4) = acc[r];
  }
}

// ---------------- tiled fp32 GEMM, BM=64 (for K=128) ----------------
template<int K, int KS>
__global__ __launch_bounds__(256,4) void k_pg(const float* __restrict__ feat,
    const float* __restrict__ W, float* __restrict__ part, int rows){
  __shared__ float As[64*64];
  __shared__ float Ws[64*64];
  const int KSL = K/KS;
  const int STEPS = KSL/64;
  int t = threadIdx.x;
  int w = t>>6, lane = t&63;
  int c = t&15, rg = t>>4;
  int rowb = blockIdx.x*64;
  int k0 = blockIdx.y*KSL;
  float4 acc[4];
  #pragma unroll
  for(int r=0;r<4;r++) acc[r] = make_float4(0.f,0.f,0.f,0.f);

  for(int s=0; s<STEPS; ++s){
    if(s) __syncthreads();
    int kk = k0 + s*64;
    #pragma unroll
    for(int i=0;i<4;i++){
      int q = w*4 + i;
      int grow = rowb + q*4 + (lane>>4); if(grow > rows-1) grow = rows-1;
      int seg = (lane&15) ^ (q&3);
      gld16(feat + (size_t)grow*K + kk + seg*4, As + q*256);
    }
    #pragma unroll
    for(int i=0;i<4;i++){
      int q = w*4 + i;
      gld16(W + (size_t)(kk + q*4)*64 + lane*4, Ws + q*256);
    }
    __syncthreads();
    #pragma unroll 4
    for(int k4=0;k4<16;k4++){
      float4 wv[4], a4[4];
      #pragma unroll
      for(int j=0;j<4;j++) wv[j] = *(const float4*)&Ws[(k4*4+j)*64 + c*4];
      int sw = (k4 ^ (rg&3))*4;
      #pragma unroll
      for(int r=0;r<4;r++) a4[r] = *(const float4*)&As[(rg*4+r)*64 + sw];
      #pragma unroll
      for(int r=0;r<4;r++){
        acc[r].x += a4[r].x*wv[0].x + a4[r].y*wv[1].x + a4[r].z*wv[2].x + a4[r].w*wv[3].x;
        acc[r].y += a4[r].x*wv[0].y + a4[r].y*wv[1].y + a4[r].z*wv[2].y + a4[r].w*wv[3].y;
        acc[r].z += a4[r].x*wv[0].z + a4[r].y*wv[1].z + a4[r].z*wv[2].z + a4[r].w*wv[3].z;
        acc[r].w += a4[r].x*wv[0].w + a4[r].y*wv[1].w + a4[r].z*wv[2].w + a4[r].w*wv[3].w;
      }
    }
  }
  float* pb = part + (size_t)blockIdx.y*rows*64;
  #pragma unroll
  for(int r=0;r<4;r++){
    int row = rowb + rg*4 + r;
    if(row < rows) *(float4*)(pb + (size_t)row*64 + c*4) = acc[r];
  }
}

// reduce K-split partials + bias + leaky + l2norm -> interleaved xc (row stride 128)
template<int KS>
__global__ void k_projfin(const float* __restrict__ part, const float* __restrict__ bias,
    float* __restrict__ xout, int rows){
  int idx = blockIdx.x*blockDim.x + threadIdx.x;
  int g = idx>>4, c = idx&15;
  if(g>=rows) return;
  float4 o = make_float4(0.f,0.f,0.f,0.f);
  #pragma unroll
  for(int s=0;s<KS;s++){
    float4 p = *(const float4*)(part + ((size_t)s*rows + g)*64 + 4*c);
    o.x += p.x; o.y += p.y; o.z += p.z; o.w += p.w;
  }
  float4 bb = *(const float4*)(bias + 4*c);
  o.x = leaky(o.x + bb.x); o.y = leaky(o.y + bb.y);
  o.z = leaky(o.z + bb.z); o.w = leaky(o.w + bb.w);
  *(float4*)(xout + (size_t)g*128 + 4*c) = qnorm(o);
}

// ---------------- fused 3-iteration routing; 32 lanes/node (v-half | a-half) ----------------
__global__ void k_route3(const float* __restrict__ pv, const float* __restrict__ pa,
    float* __restrict__ xc, const int* __restrict__ ptr, const int* __restrict__ col){
  int g = blockIdx.x*8 + (threadIdx.x>>5);
  int c = threadIdx.x & 31;            // float4 index into 128-dim interleaved row
  if(g >= NU) return;
  float4 u = (c<16) ? *(const float4*)(pv + (size_t)g*64 + 4*c)
                    : *(const float4*)(pa + (size_t)g*64 + 4*(c-16));
  u = qnorm(u);                        // per-half norm (qred16 stays in half)
  int e0 = ptr[g], e1 = ptr[g+1];
  #pragma unroll 1
  for(int it=0; it<3; ++it){
    float s = 0.f;
    float4 acc = make_float4(0.f,0.f,0.f,0.f);
    int e = e0;
    for(; e+1<e1; e+=2){
      int s0 = col[e], s1 = col[e+1];
      float4 j0 = *(const float4*)(xc + (size_t)s0*128 + 4*c);
      float4 j1 = *(const float4*)(xc + (size_t)s1*128 + 4*c);
      float d0 = qred16(dot4(u,j0));
      float d1 = qred16(dot4(u,j1));
      float w0 = __expf(d0), w1 = __expf(d1);   // unit-norm rows -> no max pass
      s += w0 + w1;
      acc.x += w0*j0.x + w1*j1.x; acc.y += w0*j0.y + w1*j1.y;
      acc.z += w0*j0.z + w1*j1.z; acc.w += w0*j0.w + w1*j1.w;
    }
    if(e<e1){
      float4 j0 = *(const float4*)(xc + (size_t)col[e]*128 + 4*c);
      float w0 = __expf(qred16(dot4(u,j0)));
      s += w0;
      acc.x += w0*j0.x; acc.y += w0*j0.y; acc.z += w0*j0.z; acc.w += w0*j0.w;
    }
    float inv = 1.f/(s + EPSF);
    u = qnorm(make_float4(u.x + acc.x*inv, u.y + acc.y*inv,
                          u.z + acc.z*inv, u.w + acc.w*inv));
  }
  *(float4*)(xc + (size_t)g*128 + 4*c) = u;
}

// ---------------- final GAT over doubled edges; 32 lanes/node ----------------
__global__ void k_fgat(const float* __restrict__ xc,
    float* __restrict__ av, float* __restrict__ aa,
    float* __restrict__ sv, float* __restrict__ sa,
    const int* __restrict__ ptr, const int* __restrict__ col,
    float* __restrict__ out){
  int g = blockIdx.x*8 + (threadIdx.x>>5);
  int c = threadIdx.x & 31;
  if(g >= NN) return;
  float4 xi = *(const float4*)(xc + (size_t)g*128 + 4*c);
  int e0 = ptr[g], e1 = ptr[g+1];
  float s = 0.f;
  float4 acc = make_float4(0.f,0.f,0.f,0.f);
  int e = e0;
  for(; e+1<e1; e+=2){
    int s0 = col[e], s1 = col[e+1];
    float4 j0 = *(const float4*)(xc + (size_t)s0*128 + 4*c);
    float4 j1 = *(const float4*)(xc + (size_t)s1*128 + 4*c);
    float d0 = qred16(dot4(xi,j0));
    float d1 = qred16(dot4(xi,j1));
    float w0 = __expf(d0), w1 = __expf(d1);
    if(c==0){  av[e] = w0; av[e+1] = w1; }
    if(c==16){ aa[e] = w0; aa[e+1] = w1; }
    s += w0 + w1;
    acc.x += w0*j0.x + w1*j1.x; acc.y += w0*j0.y + w1*j1.y;
    acc.z += w0*j0.z + w1*j1.z; acc.w += w0*j0.w + w1*j1.w;
  }
  if(e<e1){
    float4 j0 = *(const float4*)(xc + (size_t)col[e]*128 + 4*c);
    float w0 = __expf(qred16(dot4(xi,j0)));
    if(c==0)  av[e] = w0;
    if(c==16) aa[e] = w0;
    s += w0;
    acc.x += w0*j0.x; acc.y += w0*j0.y; acc.z += w0*j0.z; acc.w += w0*j0.w;
  }
  float inv = 1.f/(s + EPSF);
  if(c==0)  sv[g] = inv;
  if(c==16) sa[g] = inv;
  float4 o = make_float4(xi.x + leaky(acc.x*inv), xi.y + leaky(acc.y*inv),
                         xi.z + leaky(acc.z*inv), xi.w + leaky(acc.w*inv));
  *(float4*)(out + (size_t)g*192 + 64 + 4*c) = o;   // 64..191 = [v_rep|a_rep]
}

// ---------------- fused SAGE layer (+inline edge-weight computation for layer 1) ----------------
// EPI 0: compute wb[e] inline from alphas/conf, out=leaky(..) stride 64
// EPI 1: read wb, out = a0+a1+leaky(..) stride 192
template<int EPI>
__global__ __launch_bounds__(256) void k_aggmm(const float* __restrict__ xin,
    const float* __restrict__ av, const float* __restrict__ aa,
    const float* __restrict__ sv, const float* __restrict__ sa,
    const float* __restrict__ conf, float* __restrict__ wb,
    const int* __restrict__ ptr, const int* __restrict__ col,
    const float* __restrict__ Wm, const float* __restrict__ bm,
    const float* __restrict__ a0, const float* __restrict__ a1,
    float* __restrict__ outp){
  __shared__ float Wl[64*64];
  __shared__ float rowbuf[16*68];
  int t = threadIdx.x;
  #pragma unroll
  for(int i=0;i<4;i++)
    *(float4*)&Wl[i*1024 + t*4] = *(const float4*)&Wm[i*1024 + t*4];
  int grp = t>>4, c = t&15;
  int g = blockIdx.x*16 + grp;
  bool ok = g < NN;
  int gg = ok ? g : 0;
  int e0 = ok ? ptr[g] : 0, e1 = ok ? ptr[g+1] : 0;
  float c0=0.f, c1=0.f, isv=0.f, isa=0.f;
  if(EPI==0){ c0 = conf[2*gg]; c1 = conf[2*gg+1]; isv = sv[gg]; isa = sa[gg]; }
  float4 acc = make_float4(0.f,0.f,0.f,0.f);
  int e = e0;
  for(; e+1<e1; e+=2){
    float w0, w1;
    if(EPI==0){
      w0 = fmaxf(fmaxf(av[e]*isv*c0,   aa[e]*isa*c1),   0.f);
      w1 = fmaxf(fmaxf(av[e+1]*isv*c0, aa[e+1]*isa*c1), 0.f);
      if(c==0){ wb[e] = w0; wb[e+1] = w1; }
    }else{
      w0 = wb[e]; w1 = wb[e+1];
    }
    float4 x0v = *(const float4*)(xin + (size_t)col[e]*64 + 4*c);
    float4 x1v = *(const float4*)(xin + (size_t)col[e+1]*64 + 4*c);
    acc.x += w0*x0v.x + w1*x1v.x; acc.y += w0*x0v.y + w1*x1v.y;
    acc.z += w0*x0v.z + w1*x1v.z; acc.w += w0*x0v.w + w1*x1v.w;
  }
  if(e<e1){
    float w0;
    if(EPI==0){
      w0 = fmaxf(fmaxf(av[e]*isv*c0, aa[e]*isa*c1), 0.f);
      if(c==0) wb[e] = w0;
    }else w0 = wb[e];
    float4 x0v = *(const float4*)(xin + (size_t)col[e]*64 + 4*c);
    acc.x += w0*x0v.x; acc.y += w0*x0v.y; acc.z += w0*x0v.z; acc.w += w0*x0v.w;
  }
  __syncthreads();
  *(float4*)&rowbuf[grp*68 + c*4] = acc;
  float4 o = make_float4(0.f,0.f,0.f,0.f);
  #pragma unroll 4
  for(int k4=0;k4<16;k4++){
    float4 a4 = *(const float4*)&rowbuf[grp*68 + k4*4];
    float4 w0 = *(const float4*)&Wl[(k4*4+0)*64 + c*4];
    float4 w1 = *(const float4*)&Wl[(k4*4+1)*64 + c*4];
    float4 w2 = *(const float4*)&Wl[(k4*4+2)*64 + c*4];
    float4 w3 = *(const float4*)&Wl[(k4*4+3)*64 + c*4];
    o.x += a4.x*w0.x + a4.y*w1.x + a4.z*w2.x + a4.w*w3.x;
    o.y += a4.x*w0.y + a4.y*w1.y + a4.z*w2.y + a4.w*w3.y;
    o.z += a4.x*w0.z + a4.y*w1.z + a4.z*w2.z + a4.w*w3.z;
    o.w += a4.x*w0.w + a4.y*w1.w + a4.z*w2.w + a4.w*w3.w;
  }
  if(!ok) return;
  float4 bb = *(const float4*)(bm + 4*c);
  o.x = leaky(o.x + bb.x); o.y = leaky(o.y + bb.y);
  o.z = leaky(o.z + bb.z); o.w = leaky(o.w + bb.w);
  if(EPI==0){
    *(float4*)(outp + (size_t)g*64 + 4*c) = o;
  }else{
    float4 v0 = *(const float4*)(a0 + (size_t)g*64 + 4*c);
    float4 v1 = *(const float4*)(a1 + (size_t)g*64 + 4*c);
    o.x += v0.x + v1.x; o.y += v0.y + v1.y;
    o.z += v0.z + v1.z; o.w += v0.w + v1.w;
    *(float4*)(outp + (size_t)g*192 + 4*c) = o;
  }
}

extern "C" void kernel_launch(void* const* d_in, const int* in_sizes, int n_in,
                              void* d_out, int out_size, void* d_ws, size_t ws_size,
                              hipStream_t stream){
  const int*   edge_u = (const int*)  d_in[0];
  const int*   edge_i = (const int*)  d_in[1];
  const float* v_feat = (const float*)d_in[2];
  const float* a_feat = (const float*)d_in[3];
  const float* pref_v = (const float*)d_in[4];
  const float* pref_a = (const float*)d_in[5];
  const float* Wv     = (const float*)d_in[6];
  const float* bv     = (const float*)d_in[7];
  const float* Wa     = (const float*)d_in[8];
  const float* ba     = (const float*)d_in[9];
  const float* id_emb = (const float*)d_in[10];
  const float* W1     = (const float*)d_in[11];
  const float* b1     = (const float*)d_in[12];
  const float* W2     = (const float*)d_in[13];
  const float* b2     = (const float*)d_in[14];
  const float* conf   = (const float*)d_in[15];
  float* out = (float*)d_out;

  char* p = (char*)d_ws;
  auto alloc = [&](size_t bytes)->void*{
    void* q = p; p += (bytes + 255) & ~(size_t)255; return q;
  };
  int*   cnt  = (int*)  alloc((size_t)NN*4);
  int*   loc  = (int*)  alloc((size_t)NN*4);
  int*   bsum = (int*)  alloc((size_t)NB_SCAN*4);
  int*   boff = (int*)  alloc((size_t)NB_SCAN*4);
  int*   ptr  = (int*)  alloc((size_t)(NN+1)*4);
  int*   cur  = (int*)  alloc((size_t)NN*4);
  int*   colA = (int*)  alloc((size_t)E2*4);
  float* xc   = (float*)alloc((size_t)NN*128*4);  // interleaved [v|a] per node
  float* x0   = (float*)alloc((size_t)NN*64*4);   // GEMM partials alias x0+x1
  float* x1   = (float*)alloc((size_t)NN*64*4);
  float* av   = (float*)alloc((size_t)E2*4);
  float* aa   = (float*)alloc((size_t)E2*4);
  float* sv   = (float*)alloc((size_t)NN*4);
  float* sa   = (float*)alloc((size_t)NN*4);
  float* wb   = (float*)alloc((size_t)E2*4);
  float* part = x0;  // 4*NI*64*4 = 30.7MB <= x0+x1 (41MB); dead before x0/x1 written

  // CSR build (dst2 = [edge_u ; edge_i])
  hipMemsetAsync(cnt, 0, (size_t)NN*4, stream);
  k_hist<<<(EE+255)/256, 256, 0, stream>>>(edge_u, edge_i, cnt);
  k_scanA<<<NB_SCAN, 256, 0, stream>>>(cnt, loc, bsum);
  k_scanB<<<1, 512, 0, stream>>>(bsum, boff);
  k_scanC<<<NB_SCAN, 256, 0, stream>>>(loc, boff, ptr, cur);
  k_scatter<<<(EE+255)/256, 256, 0, stream>>>(edge_u, edge_i, cur, colA);

  // feature projections (tiled GEMM with k-split, then reduce+epilogue into xc item rows)
  k_pg128<2048,4><<<dim3((NI+127)/128, 4), 256, 0, stream>>>(v_feat, Wv, part, NI);
  k_projfin<4><<<(NI*16+255)/256, 256, 0, stream>>>(part, bv, xc + (size_t)NU*128, NI);
  k_pg<128,2><<<dim3((NI+63)/64, 2), 256, 0, stream>>>(a_feat, Wa, part, NI);
  k_projfin<2><<<(NI*16+255)/256, 256, 0, stream>>>(part, ba, xc + (size_t)NU*128 + 64, NI);

  // id_emb l2norm (part is dead now)
  k_l2n4<<<(NN*16+255)/256, 256, 0, stream>>>(id_emb, x0, NN);

  // fused 3-iteration routing (both modalities, pref l2norm folded in)
  k_route3<<<(NU+7)/8, 256, 0, stream>>>(pref_v, pref_a, xc, ptr, colA);

  // final GAT (both modalities) -> v_rep/a_rep + raw alphas
  k_fgat<<<(NN+7)/8, 256, 0, stream>>>(xc, av, aa, sv, sa, ptr, colA, out);

  // egcn: fused agg+dense (layer 1 computes edge weights inline), twice
  k_aggmm<0><<<(NN+15)/16, 256, 0, stream>>>(x0, av, aa, sv, sa, conf, wb,
                                             ptr, colA, W1, b1, nullptr, nullptr, x1);
  k_aggmm<1><<<(NN+15)/16, 256, 0, stream>>>(x1, av, aa, sv, sa, conf, wb,
                                             ptr, colA, W2, b2, x0, x1, out);
}